// Round 6
// baseline (4937.463 us; speedup 1.0000x reference)
//
#include <hip/hip_runtime.h>
#include <math.h>

// Problem dims
#define S_LEN  512
#define BATCH  64
#define E_DIM  512
#define H_DIM  512
#define G4     2048          // 4*H
#define VOCAB  32000
#define NWG    16            // persistent LSTM workgroups (1 per 16 CUs; trivially co-resident)

typedef int v4i __attribute__((ext_vector_type(4)));

// Workspace layout (bytes). Total ~18.1 MiB.
#define O_BAR   0                         // unsigned barrier counter
#define O_MAX   256                       // 4 uints: maxabs emb, ih, hh, fc
#define O_H8    512                       // 2*64*512 int8 double buffer (65536 B)
#define O_FC8   66048                     // 1024 int8
#define O_WIH8  67072                     // 2048*512 int8 (1 MiB)
#define O_WHH8  (O_WIH8 + 1048576)
#define O_X8    (O_WHH8 + 1048576)        // 512 steps * 64 batch * 512 int8 (16 MiB), t-major

__device__ __forceinline__ float clampf(float x, float lo, float hi) {
    return fminf(fmaxf(x, lo), hi);
}

// k = ceil(log2(maxabs/127)) computed exactly via frexp (no transcendental):
// t = f*2^e, f in [0.5,1): ceil(log2 t) = e-1 if f==0.5 else e.
__device__ __forceinline__ int scale_exp(float maxabs) {
    double t = (double)maxabs / 127.0;
    int e; double f = frexp(t, &e);
    return (f == 0.5) ? (e - 1) : e;
}

// ---- XLA-CPU / Eigen fast tanh (f32), bit-exact replication -----------------
// R6 theory: the golden was generated by jax on CPU; XLA emits this rational
// polynomial (NOT libm tanh) for f32 tanh, and expands logistic(x) as
// 0.5 + 0.5*tanh(0.5x). Its ~3-ulp systematic offset from correctly-rounded
// tanh explains the R2==R3==R5 bit-identical mismatch (all my CR variants
// agree with each other but not with the ref's rint(tanh*128) flips).
// Coefficients: Eigen generic_fast_tanh_float == XLA elemental_ir_emitter.
__device__ __forceinline__ float xla_tanhf(float x) {
    // |x| < 0.0004 -> x (XLA kCanUseApprox); irrelevant to codes (rounds to 0)
    if (fabsf(x) < 0.0004f) return x;
    float xc = fminf(fmaxf(x, -7.90531110763549805f), 7.90531110763549805f);
    float x2 = __fmul_rn(xc, xc);
    float p = fmaf(x2, -2.76076847742355e-16f, 2.00018790482477e-13f); // a13,a11
    p = fmaf(x2, p, -8.60467152213735e-11f);   // a9
    p = fmaf(x2, p, 5.12229709037114e-08f);    // a7
    p = fmaf(x2, p, 1.48572235717979e-05f);    // a5
    p = fmaf(x2, p, 6.37261928875436e-04f);    // a3
    p = fmaf(x2, p, 4.89352455891786e-03f);    // a1
    p = __fmul_rn(xc, p);
    float q = fmaf(x2, 1.19825839466702e-06f, 1.18534705686654e-04f);  // b6,b4
    q = fmaf(x2, q, 2.26843463243900e-03f);    // b2
    q = fmaf(x2, q, 4.89352518554385e-03f);    // b0
    return __fdiv_rn(p, q);
}

// ---------------- maxabs reduction ----------------
__global__ void k_maxabs(const float* __restrict__ x, int n, unsigned* __restrict__ out) {
    unsigned m = 0;
    for (int i = blockIdx.x * blockDim.x + threadIdx.x; i < n; i += gridDim.x * blockDim.x)
        m = max(m, __float_as_uint(fabsf(x[i])));
    #pragma unroll
    for (int o = 32; o > 0; o >>= 1) {
        unsigned other = (unsigned)__shfl_down((int)m, o, 64);
        m = max(m, other);
    }
    __shared__ unsigned sm[4];
    if ((threadIdx.x & 63) == 0) sm[threadIdx.x >> 6] = m;
    __syncthreads();
    if (threadIdx.x == 0) {
        unsigned r = sm[0];
        for (int w = 1; w < (int)(blockDim.x >> 6); w++) r = max(r, sm[w]);
        atomicMax(out, r);
    }
}

// ---------------- weight quantization (exact: pow2 scale) ----------------
__global__ void k_quantw(const float* __restrict__ w, int n, const unsigned* __restrict__ mx,
                         signed char* __restrict__ q) {
    float inv = ldexpf(1.0f, -scale_exp(__uint_as_float(*mx)));
    for (int i = blockIdx.x * blockDim.x + threadIdx.x; i < n; i += gridDim.x * blockDim.x) {
        float v = clampf(rintf(w[i] * inv), -128.0f, 127.0f);
        q[i] = (signed char)(int)v;
    }
}

// ---------------- embedding lookup + double quantization (exact: pow2 scales) ----
__global__ void k_embed(const float* __restrict__ emb, const int* __restrict__ text,
                        const unsigned* __restrict__ mx, signed char* __restrict__ x8) {
    int row = blockIdx.x;                       // b*S + s (text is [B,S] row-major)
    int b = row >> 9, s = row & 511;
    int tok = text[row];
    int ke = scale_exp(__uint_as_float(*mx));
    float inv = ldexpf(1.0f, -ke);
    float sc2 = ldexpf(1.0f, ke + 4);           // s_e / 2^-4 (pow2, all products exact)
    const float4* src = (const float4*)(emb + (size_t)tok * E_DIM);
    char4* dst = (char4*)(x8 + (size_t)(s * BATCH + b) * E_DIM);
    float4 v = src[threadIdx.x];                // 128 threads * 4 = 512
    char4 c;
    float q;
    q = clampf(rintf(v.x * inv), -128.f, 127.f); c.x = (signed char)(int)clampf(rintf(q * sc2), -128.f, 127.f);
    q = clampf(rintf(v.y * inv), -128.f, 127.f); c.y = (signed char)(int)clampf(rintf(q * sc2), -128.f, 127.f);
    q = clampf(rintf(v.z * inv), -128.f, 127.f); c.z = (signed char)(int)clampf(rintf(q * sc2), -128.f, 127.f);
    q = clampf(rintf(v.w * inv), -128.f, 127.f); c.w = (signed char)(int)clampf(rintf(q * sc2), -128.f, 127.f);
    dst[threadIdx.x] = c;
}

// ---------------- persistent fused LSTM (input GEMM + recurrence) ----------------
// f32 elementwise chain (R5, proven to match np-f32 association); transcendentals
// via XLA-CPU's polynomial (xla_tanhf) — tanh(c), gate-tanh LUT, and sigmoid LUT
// as 0.5 + 0.5*tanh(0.5x) (XLA logistic_expander form).
__global__ __launch_bounds__(256, 1) void k_lstm(
    const signed char* __restrict__ wih8, const signed char* __restrict__ whh8,
    const signed char* __restrict__ x8, const float* __restrict__ b_ih,
    const float* __restrict__ b_hh, const unsigned* __restrict__ mx,
    signed char* __restrict__ h8, unsigned* __restrict__ bar) {
    __shared__ __attribute__((aligned(16))) signed char wih_lds[128 * 528]; // rows padded 512->528
    __shared__ __attribute__((aligned(16))) signed char whh_lds[128 * 528];
    __shared__ float lut_sig[256];   // qd(sigmoid(v), 2^-8, 0, 255), v=(i-128)/8
    __shared__ float lut_tnh[256];   // qd(tanh(v), 2^-7, -128, 127)

    const int g = blockIdx.x;
    const int tid = threadIdx.x;
    const int wv = tid >> 6, lane = tid & 63, l15 = lane & 15, qd4 = lane >> 4;
    const float sih = ldexpf(1.0f, scale_exp(__uint_as_float(mx[1])) - 4);
    const float shh = ldexpf(1.0f, scale_exp(__uint_as_float(mx[2])) - 4);

    // Gate LUTs via the XLA formulas (f32 ops at every np/XLA op boundary)
    if (tid < 256) {
        float v = (float)(tid - 128) * 0.125f;                    // exact
        float sg = __fadd_rn(0.5f, __fmul_rn(0.5f, xla_tanhf(__fmul_rn(0.5f, v))));
        float sc = clampf(rintf(__fmul_rn(sg, 256.0f)), 0.0f, 255.0f);
        lut_sig[tid] = sc * 0.00390625f;                          // exact dyadic
        float th = xla_tanhf(v);
        float tc = clampf(rintf(__fmul_rn(th, 128.0f)), -128.0f, 127.0f);
        lut_tnh[tid] = tc * 0.0078125f;                           // exact dyadic
    }

    // Stage both weight slices: local row r -> global row (r>>5)*512 + g*32 + (r&31)
    for (int it = 0; it < 16; it++) {
        int idx = it * 256 + tid;               // 0..4095 chunks of 16B
        int r = idx >> 5, cc = (idx & 31) * 16;
        int grow = (r >> 5) * 512 + g * 32 + (r & 31);
        *(v4i*)(wih_lds + r * 528 + cc) = *(const v4i*)(wih8 + (size_t)grow * 512 + cc);
        *(v4i*)(whh_lds + r * 528 + cc) = *(const v4i*)(whh8 + (size_t)grow * 512 + cc);
    }
    __syncthreads();

    // per-lane biases for the 8 N-tiles (col depends only on l15)
    float bi[8], bh[8];
    #pragma unroll
    for (int nt = 0; nt < 8; nt++) {
        int nl = nt * 16 + l15;
        int col = (nl >> 5) * 512 + g * 32 + (nl & 31);
        bi[nt] = b_ih[col];
        bh[nt] = b_hh[col];
    }

    float cst[2][4];                            // c state in f32
    #pragma unroll
    for (int jh = 0; jh < 2; jh++)
        #pragma unroll
        for (int r = 0; r < 4; r++) cst[jh][r] = 0.0f;

    // input-gate int accumulators for the CURRENT step
    v4i xacc[8];
    {   // preloop: step 0
        v4i xfr[8];
        const signed char* xrow = x8 + (size_t)(0 * BATCH + wv * 16 + l15) * 512 + qd4 * 16;
        #pragma unroll
        for (int k = 0; k < 8; k++) xfr[k] = *(const v4i*)(xrow + k * 64);
        #pragma unroll
        for (int nt = 0; nt < 8; nt++) {
            v4i a = (v4i){0, 0, 0, 0};
            #pragma unroll
            for (int k = 0; k < 8; k++) {
                v4i bf = *(const v4i*)(wih_lds + (nt * 16 + l15) * 528 + k * 64 + qd4 * 16);
                a = __builtin_amdgcn_mfma_i32_16x16x64_i8(xfr[k], bf, a, 0, 0, 0);
            }
            xacc[nt] = a;
        }
    }

    for (int t = 0; t < S_LEN; t++) {
        const signed char* hin = h8 + (t & 1) * (BATCH * H_DIM);
        signed char* hout = h8 + ((t + 1) & 1) * (BATCH * H_DIM);

        // h fragments for this wave's 16 batches, all K
        v4i afr[8];
        #pragma unroll
        for (int k = 0; k < 8; k++)
            afr[k] = *(const v4i*)(hin + (wv * 16 + l15) * 512 + k * 64 + qd4 * 16);

        // recurrent MFMAs + f32 pre-activations, ref association:
        // ((exact_x + b_ih) + b_hh) + exact_h  — only the adds round.
        float pre[8][4];
        #pragma unroll
        for (int nt = 0; nt < 8; nt++) {
            v4i hacc = (v4i){0, 0, 0, 0};
            #pragma unroll
            for (int k = 0; k < 8; k++) {
                v4i bf = *(const v4i*)(whh_lds + (nt * 16 + l15) * 528 + k * 64 + qd4 * 16);
                hacc = __builtin_amdgcn_mfma_i32_16x16x64_i8(afr[k], bf, hacc, 0, 0, 0);
            }
            #pragma unroll
            for (int r = 0; r < 4; r++)
                pre[nt][r] = __fadd_rn(
                    __fadd_rn(__fadd_rn(__fmul_rn((float)xacc[nt][r], sih), bi[nt]), bh[nt]),
                    __fmul_rn((float)hacc[r], shh));
        }

        // gate math (f32); lane cell (jh,r) -> b = wv*16+qd4*4+r, j = g*32+jh*16+l15
        #pragma unroll
        for (int jh = 0; jh < 2; jh++)
            #pragma unroll
            for (int r = 0; r < 4; r++) {
                int ii = (int)clampf(rintf(__fmul_rn(pre[0 + jh][r], 8.0f)), -128.f, 127.f) + 128;
                int fi = (int)clampf(rintf(__fmul_rn(pre[2 + jh][r], 8.0f)), -128.f, 127.f) + 128;
                int gi = (int)clampf(rintf(__fmul_rn(pre[4 + jh][r], 8.0f)), -128.f, 127.f) + 128;
                int oi = (int)clampf(rintf(__fmul_rn(pre[6 + jh][r], 8.0f)), -128.f, 127.f) + 128;
                float iq = lut_sig[ii], fq = lut_sig[fi], oq = lut_sig[oi];
                float gq = lut_tnh[gi];
                // c = f*c + i*g: f32 separate mul/mul/add (i*g exact dyadic)
                float c = __fadd_rn(__fmul_rn(fq, cst[jh][r]), __fmul_rn(iq, gq));
                cst[jh][r] = c;
                // tanh(c) via the XLA polynomial (the non-CR ref implementation)
                float tc32 = xla_tanhf(c);
                float tq = clampf(rintf(__fmul_rn(tc32, 128.0f)), -128.f, 127.f) * 0.0078125f;
                float hv = __fmul_rn(oq, tq);           // exact dyadic product
                int hc = (int)clampf(rintf(__fmul_rn(hv, 16.0f)), -128.f, 127.f);
                int b = wv * 16 + qd4 * 4 + r;
                hout[b * 512 + g * 32 + jh * 16 + l15] = (signed char)hc;
            }

        // release stores, arrive at device barrier
        __threadfence();
        __syncthreads();
        if (tid == 0)
            __hip_atomic_fetch_add(bar, 1u, __ATOMIC_ACQ_REL, __HIP_MEMORY_SCOPE_AGENT);

        // hide the t+1 input-gate GEMM behind the barrier wait
        if (t + 1 < S_LEN) {
            v4i xfr[8];
            const signed char* xrow = x8 + (size_t)((t + 1) * BATCH + wv * 16 + l15) * 512 + qd4 * 16;
            #pragma unroll
            for (int k = 0; k < 8; k++) xfr[k] = *(const v4i*)(xrow + k * 64);
            #pragma unroll
            for (int nt = 0; nt < 8; nt++) {
                v4i a = (v4i){0, 0, 0, 0};
                #pragma unroll
                for (int k = 0; k < 8; k++) {
                    v4i bf = *(const v4i*)(wih_lds + (nt * 16 + l15) * 528 + k * 64 + qd4 * 16);
                    a = __builtin_amdgcn_mfma_i32_16x16x64_i8(xfr[k], bf, a, 0, 0, 0);
                }
                xacc[nt] = a;
            }
        }

        // spin until all 16 WGs finished step t, then acquire
        if (tid == 0) {
            unsigned target = (unsigned)(t + 1) * NWG;
            while (__hip_atomic_load(bar, __ATOMIC_ACQUIRE, __HIP_MEMORY_SCOPE_AGENT) < target)
                __builtin_amdgcn_s_sleep(1);
        }
        __syncthreads();
        __threadfence();   // acquire: invalidate stale caches before reading remote h
    }
}

// ---------------- final FC: out[1,64,2] = h_T @ fc_q^T (exact int dot) ----------
__global__ void k_fc(const signed char* __restrict__ h8, const signed char* __restrict__ fc8,
                     const unsigned* __restrict__ mx_fc, float* __restrict__ out) {
    int tid = threadIdx.x;              // 128 threads = 64 b * 2 o
    int b = tid >> 1, o = tid & 1;
    const char4* hp = (const char4*)(h8 + b * 512);
    const char4* wp = (const char4*)(fc8 + o * 512);
    int s = 0;
    for (int i = 0; i < 128; i++) {
        char4 a = hp[i], w = wp[i];
        s += a.x * w.x + a.y * w.y + a.z * w.z + a.w * w.w;
    }
    float sc = ldexpf(1.0f, scale_exp(__uint_as_float(*mx_fc)) - 4);
    out[b * 2 + o] = (float)s * sc;     // exact: s < 2^23, pow2 scale
}

extern "C" void kernel_launch(void* const* d_in, const int* in_sizes, int n_in,
                              void* d_out, int out_size, void* d_ws, size_t ws_size,
                              hipStream_t stream) {
    (void)in_sizes; (void)n_in; (void)out_size; (void)ws_size;
    const int*   text = (const int*)d_in[0];
    // d_in[1] = text_lengths: unused by the reference
    const float* emb  = (const float*)d_in[2];
    const float* w_ih = (const float*)d_in[3];
    const float* w_hh = (const float*)d_in[4];
    const float* b_ih = (const float*)d_in[5];
    const float* b_hh = (const float*)d_in[6];
    const float* fc_w = (const float*)d_in[7];

    char* ws = (char*)d_ws;
    unsigned*    bar  = (unsigned*)(ws + O_BAR);
    unsigned*    mx   = (unsigned*)(ws + O_MAX);
    signed char* h8   = (signed char*)(ws + O_H8);
    signed char* fc8  = (signed char*)(ws + O_FC8);
    signed char* wih8 = (signed char*)(ws + O_WIH8);
    signed char* whh8 = (signed char*)(ws + O_WHH8);
    signed char* x8   = (signed char*)(ws + O_X8);

    // zero barrier + maxabs + h double buffer (ws is poisoned 0xAA before each call)
    hipMemsetAsync(d_ws, 0, O_H8 + 2 * BATCH * H_DIM, stream);

    k_maxabs<<<2048, 256, 0, stream>>>(emb, VOCAB * E_DIM, mx + 0);
    k_maxabs<<<256, 256, 0, stream>>>(w_ih, G4 * E_DIM, mx + 1);
    k_maxabs<<<256, 256, 0, stream>>>(w_hh, G4 * H_DIM, mx + 2);
    k_maxabs<<<1, 256, 0, stream>>>(fc_w, 2 * H_DIM, mx + 3);

    k_quantw<<<512, 256, 0, stream>>>(w_ih, G4 * E_DIM, mx + 1, wih8);
    k_quantw<<<512, 256, 0, stream>>>(w_hh, G4 * H_DIM, mx + 2, whh8);
    k_quantw<<<2, 256, 0, stream>>>(fc_w, 2 * H_DIM, mx + 3, fc8);

    k_embed<<<BATCH * S_LEN, 128, 0, stream>>>(emb, text, mx + 0, x8);

    k_lstm<<<NWG, 256, 0, stream>>>(wih8, whh8, x8, b_ih, b_hh, mx, h8, bar);

    k_fc<<<1, 128, 0, stream>>>(h8, fc8, mx + 3, (float*)d_out);
}

// Round 7
// 3724.240 us; speedup vs baseline: 1.3258x; 1.3258x over previous
//
#include <hip/hip_runtime.h>
#include <math.h>

// Problem dims
#define S_LEN  512
#define BATCH  64
#define E_DIM  512
#define H_DIM  512
#define G4     2048          // 4*H
#define VOCAB  32000
#define NWG    16            // persistent LSTM workgroups (1 per 16 CUs; trivially co-resident)

typedef int v4i __attribute__((ext_vector_type(4)));
typedef unsigned long long u64;

// Workspace layout (bytes). Total ~18.1 MiB.
#define O_BAR   0                         // unsigned barrier counter
#define O_MAX   256                       // 4 uints: maxabs emb, ih, hh, fc
#define O_H8    512                       // 2*64*512 int8 double buffer (65536 B)
#define O_FC8   66048                     // 1024 int8
#define O_WIH8  67072                     // 2048*512 int8 (1 MiB)
#define O_WHH8  (O_WIH8 + 1048576)
#define O_X8    (O_WHH8 + 1048576)        // 512 steps * 64 batch * 512 int8 (16 MiB), t-major

__device__ __forceinline__ float clampf(float x, float lo, float hi) {
    return fminf(fmaxf(x, lo), hi);
}

// k = ceil(log2(maxabs/127)) via frexp (exact, no transcendental)
__device__ __forceinline__ int scale_exp(float maxabs) {
    double t = (double)maxabs / 127.0;
    int e; double f = frexp(t, &e);
    return (f == 0.5) ? (e - 1) : e;
}

// UC (coherence-point) 16B load as two relaxed agent-scope 8B atomics.
// RELAXED => no buffer_inv/wbl2 cache maintenance (the R6 9.7us/step killer);
// sc0/sc1 bypass bits still route the access to the device-coherent point.
__device__ __forceinline__ v4i uc_load16(const signed char* p) {
    u64 lo = __hip_atomic_load((const u64*)p,       __ATOMIC_RELAXED, __HIP_MEMORY_SCOPE_AGENT);
    u64 hi = __hip_atomic_load((const u64*)(p + 8), __ATOMIC_RELAXED, __HIP_MEMORY_SCOPE_AGENT);
    union { u64 q[2]; v4i v; } u; u.q[0] = lo; u.q[1] = hi; return u.v;
}

// ---- XLA-CPU / Eigen fast tanh (f32), bit-exact vs the jax-CPU golden ------
__device__ __forceinline__ float xla_tanhf(float x) {
    if (fabsf(x) < 0.0004f) return x;
    float xc = fminf(fmaxf(x, -7.90531110763549805f), 7.90531110763549805f);
    float x2 = __fmul_rn(xc, xc);
    float p = fmaf(x2, -2.76076847742355e-16f, 2.00018790482477e-13f);
    p = fmaf(x2, p, -8.60467152213735e-11f);
    p = fmaf(x2, p, 5.12229709037114e-08f);
    p = fmaf(x2, p, 1.48572235717979e-05f);
    p = fmaf(x2, p, 6.37261928875436e-04f);
    p = fmaf(x2, p, 4.89352455891786e-03f);
    p = __fmul_rn(xc, p);
    float q = fmaf(x2, 1.19825839466702e-06f, 1.18534705686654e-04f);
    q = fmaf(x2, q, 2.26843463243900e-03f);
    q = fmaf(x2, q, 4.89352518554385e-03f);
    return __fdiv_rn(p, q);
}

// ---------------- maxabs reduction ----------------
__global__ void k_maxabs(const float* __restrict__ x, int n, unsigned* __restrict__ out) {
    unsigned m = 0;
    for (int i = blockIdx.x * blockDim.x + threadIdx.x; i < n; i += gridDim.x * blockDim.x)
        m = max(m, __float_as_uint(fabsf(x[i])));
    #pragma unroll
    for (int o = 32; o > 0; o >>= 1) {
        unsigned other = (unsigned)__shfl_down((int)m, o, 64);
        m = max(m, other);
    }
    __shared__ unsigned sm[4];
    if ((threadIdx.x & 63) == 0) sm[threadIdx.x >> 6] = m;
    __syncthreads();
    if (threadIdx.x == 0) {
        unsigned r = sm[0];
        for (int w = 1; w < (int)(blockDim.x >> 6); w++) r = max(r, sm[w]);
        atomicMax(out, r);
    }
}

// ---------------- weight quantization (exact: pow2 scale) ----------------
__global__ void k_quantw(const float* __restrict__ w, int n, const unsigned* __restrict__ mx,
                         signed char* __restrict__ q) {
    float inv = ldexpf(1.0f, -scale_exp(__uint_as_float(*mx)));
    for (int i = blockIdx.x * blockDim.x + threadIdx.x; i < n; i += gridDim.x * blockDim.x) {
        float v = clampf(rintf(w[i] * inv), -128.0f, 127.0f);
        q[i] = (signed char)(int)v;
    }
}

// ---------------- embedding lookup + double quantization (exact: pow2 scales) ----
__global__ void k_embed(const float* __restrict__ emb, const int* __restrict__ text,
                        const unsigned* __restrict__ mx, signed char* __restrict__ x8) {
    int row = blockIdx.x;                       // b*S + s (text is [B,S] row-major)
    int b = row >> 9, s = row & 511;
    int tok = text[row];
    int ke = scale_exp(__uint_as_float(*mx));
    float inv = ldexpf(1.0f, -ke);
    float sc2 = ldexpf(1.0f, ke + 4);
    const float4* src = (const float4*)(emb + (size_t)tok * E_DIM);
    char4* dst = (char4*)(x8 + (size_t)(s * BATCH + b) * E_DIM);
    float4 v = src[threadIdx.x];
    char4 c;
    float q;
    q = clampf(rintf(v.x * inv), -128.f, 127.f); c.x = (signed char)(int)clampf(rintf(q * sc2), -128.f, 127.f);
    q = clampf(rintf(v.y * inv), -128.f, 127.f); c.y = (signed char)(int)clampf(rintf(q * sc2), -128.f, 127.f);
    q = clampf(rintf(v.z * inv), -128.f, 127.f); c.z = (signed char)(int)clampf(rintf(q * sc2), -128.f, 127.f);
    q = clampf(rintf(v.w * inv), -128.f, 127.f); c.w = (signed char)(int)clampf(rintf(q * sc2), -128.f, 127.f);
    dst[threadIdx.x] = c;
}

// ---------------- persistent fused LSTM ----------------
// R7 changes (numerics untouched): fence-free h exchange (relaxed agent atomics,
// UC data path), whh slice resident in 256 VGPRs/lane (critical-path hh-GEMM has
// zero LDS reads), writer-side LDS transpose -> one 8B UC store per thread.
__global__ __launch_bounds__(256, 1) void k_lstm(
    const signed char* __restrict__ wih8, const signed char* __restrict__ whh8,
    const signed char* __restrict__ x8, const float* __restrict__ b_ih,
    const float* __restrict__ b_hh, const unsigned* __restrict__ mx,
    signed char* __restrict__ h8, unsigned* __restrict__ bar) {
    __shared__ __attribute__((aligned(16))) signed char wih_lds[128 * 528]; // rows padded 512->528
    __shared__ __attribute__((aligned(16))) signed char hstage[BATCH * 32]; // [b][jloc] codes
    __shared__ float lut_sig[256];
    __shared__ float lut_tnh[256];

    const int g = blockIdx.x;
    const int tid = threadIdx.x;
    const int wv = tid >> 6, lane = tid & 63, l15 = lane & 15, qd4 = lane >> 4;
    const float sih = ldexpf(1.0f, scale_exp(__uint_as_float(mx[1])) - 4);
    const float shh = ldexpf(1.0f, scale_exp(__uint_as_float(mx[2])) - 4);

    // Gate LUTs via XLA formulas (bit-exact policy from R6)
    if (tid < 256) {
        float v = (float)(tid - 128) * 0.125f;
        float sg = __fadd_rn(0.5f, __fmul_rn(0.5f, xla_tanhf(__fmul_rn(0.5f, v))));
        float sc = clampf(rintf(__fmul_rn(sg, 256.0f)), 0.0f, 255.0f);
        lut_sig[tid] = sc * 0.00390625f;
        float th = xla_tanhf(v);
        float tc = clampf(rintf(__fmul_rn(th, 128.0f)), -128.0f, 127.0f);
        lut_tnh[tid] = tc * 0.0078125f;
    }

    // Stage wih slice into LDS (used only in the barrier-overlap prefetch)
    for (int it = 0; it < 16; it++) {
        int idx = it * 256 + tid;               // 16B chunks
        int r = idx >> 5, cc = (idx & 31) * 16;
        int grow = (r >> 5) * 512 + g * 32 + (r & 31);
        *(v4i*)(wih_lds + r * 528 + cc) = *(const v4i*)(wih8 + (size_t)grow * 512 + cc);
    }

    // whh slice fragments -> registers (64 x v4i = 256 VGPRs/lane, 1 wave/SIMD)
    v4i whf[8][8];
    #pragma unroll
    for (int nt = 0; nt < 8; nt++) {
        int nl = nt * 16 + l15;
        size_t grow = (size_t)((nl >> 5) * 512 + g * 32 + (nl & 31)) * 512;
        #pragma unroll
        for (int k = 0; k < 8; k++)
            whf[nt][k] = *(const v4i*)(whh8 + grow + k * 64 + qd4 * 16);
    }
    __syncthreads();

    // per-lane biases for the 8 N-tiles
    float bi[8], bh[8];
    #pragma unroll
    for (int nt = 0; nt < 8; nt++) {
        int nl = nt * 16 + l15;
        int col = (nl >> 5) * 512 + g * 32 + (nl & 31);
        bi[nt] = b_ih[col];
        bh[nt] = b_hh[col];
    }

    float cst[2][4];
    #pragma unroll
    for (int jh = 0; jh < 2; jh++)
        #pragma unroll
        for (int r = 0; r < 4; r++) cst[jh][r] = 0.0f;

    // input-gate accumulators for the CURRENT step (step 0 preloop)
    v4i xacc[8];
    {
        v4i xfr[8];
        const signed char* xrow = x8 + (size_t)(wv * 16 + l15) * 512 + qd4 * 16;
        #pragma unroll
        for (int k = 0; k < 8; k++) xfr[k] = *(const v4i*)(xrow + k * 64);
        #pragma unroll
        for (int nt = 0; nt < 8; nt++) {
            v4i a = (v4i){0, 0, 0, 0};
            #pragma unroll
            for (int k = 0; k < 8; k++) {
                v4i bf = *(const v4i*)(wih_lds + (nt * 16 + l15) * 528 + k * 64 + qd4 * 16);
                a = __builtin_amdgcn_mfma_i32_16x16x64_i8(xfr[k], bf, a, 0, 0, 0);
            }
            xacc[nt] = a;
        }
    }

    for (int t = 0; t < S_LEN; t++) {
        const signed char* hin = h8 + (t & 1) * (BATCH * H_DIM);
        signed char* hout = h8 + ((t + 1) & 1) * (BATCH * H_DIM);

        // h fragments via UC loads (coherence point; no cache maintenance)
        v4i afr[8];
        const signed char* hrow = hin + (wv * 16 + l15) * 512 + qd4 * 16;
        #pragma unroll
        for (int k = 0; k < 8; k++) afr[k] = uc_load16(hrow + k * 64);

        // hh GEMM: 64 reg-resident MFMAs; combine to f32 pre-activations
        float pre[8][4];
        #pragma unroll
        for (int nt = 0; nt < 8; nt++) {
            v4i hacc = (v4i){0, 0, 0, 0};
            #pragma unroll
            for (int k = 0; k < 8; k++)
                hacc = __builtin_amdgcn_mfma_i32_16x16x64_i8(afr[k], whf[nt][k], hacc, 0, 0, 0);
            #pragma unroll
            for (int r = 0; r < 4; r++)
                pre[nt][r] = __fadd_rn(
                    __fadd_rn(__fadd_rn(__fmul_rn((float)xacc[nt][r], sih), bi[nt]), bh[nt]),
                    __fmul_rn((float)hacc[r], shh));
        }

        // gate math; lane cell (jh,r) -> b = wv*16+qd4*4+r, jloc = jh*16+l15
        #pragma unroll
        for (int jh = 0; jh < 2; jh++)
            #pragma unroll
            for (int r = 0; r < 4; r++) {
                int ii = (int)clampf(rintf(__fmul_rn(pre[0 + jh][r], 8.0f)), -128.f, 127.f) + 128;
                int fi = (int)clampf(rintf(__fmul_rn(pre[2 + jh][r], 8.0f)), -128.f, 127.f) + 128;
                int gi = (int)clampf(rintf(__fmul_rn(pre[4 + jh][r], 8.0f)), -128.f, 127.f) + 128;
                int oi = (int)clampf(rintf(__fmul_rn(pre[6 + jh][r], 8.0f)), -128.f, 127.f) + 128;
                float iq = lut_sig[ii], fq = lut_sig[fi], oq = lut_sig[oi];
                float gq = lut_tnh[gi];
                float c = __fadd_rn(__fmul_rn(fq, cst[jh][r]), __fmul_rn(iq, gq));
                cst[jh][r] = c;
                float tc32 = xla_tanhf(c);
                float tq = clampf(rintf(__fmul_rn(tc32, 128.0f)), -128.f, 127.f) * 0.0078125f;
                float hv = __fmul_rn(oq, tq);
                int hc = (int)clampf(rintf(__fmul_rn(hv, 16.0f)), -128.f, 127.f);
                int b = wv * 16 + qd4 * 4 + r;
                hstage[b * 32 + jh * 16 + l15] = (signed char)hc;
            }
        __syncthreads();   // hstage complete (also drains outstanding vmem)

        // one coalesced 8B UC store per thread: b = tid>>2, chunk = tid&3
        {
            u64 v = *(const u64*)(hstage + tid * 8);
            __hip_atomic_store((u64*)(hout + (tid >> 2) * 512 + g * 32 + (tid & 3) * 8),
                               v, __ATOMIC_RELAXED, __HIP_MEMORY_SCOPE_AGENT);
        }
        __syncthreads();   // compiler drains vmcnt(0): stores acked at coherence point

        if (tid == 0)      // arrive (relaxed: no cache maintenance)
            __hip_atomic_fetch_add(bar, 1u, __ATOMIC_RELAXED, __HIP_MEMORY_SCOPE_AGENT);

        // t+1 input-gate GEMM, overlapped with other WGs' arrivals
        if (t + 1 < S_LEN) {
            v4i xfr[8];
            const signed char* xrow = x8 + (size_t)((t + 1) * BATCH + wv * 16 + l15) * 512 + qd4 * 16;
            #pragma unroll
            for (int k = 0; k < 8; k++) xfr[k] = *(const v4i*)(xrow + k * 64);
            #pragma unroll
            for (int nt = 0; nt < 8; nt++) {
                v4i a = (v4i){0, 0, 0, 0};
                #pragma unroll
                for (int k = 0; k < 8; k++) {
                    v4i bf = *(const v4i*)(wih_lds + (nt * 16 + l15) * 528 + k * 64 + qd4 * 16);
                    a = __builtin_amdgcn_mfma_i32_16x16x64_i8(xfr[k], bf, a, 0, 0, 0);
                }
                xacc[nt] = a;
            }
        }

        // spin (relaxed polls -> no buffer_inv per iteration)
        if (tid == 0) {
            unsigned target = (unsigned)(t + 1) * NWG;
            while (__hip_atomic_load(bar, __ATOMIC_RELAXED, __HIP_MEMORY_SCOPE_AGENT) < target)
                __builtin_amdgcn_s_sleep(1);
        }
        __syncthreads();
    }
}

// ---------------- final FC: out[1,64,2] = h_T @ fc_q^T (exact int dot) ----------
// h read via UC loads: h8 was written cache-bypassing; normal reads could hit
// stale zero lines left valid in some L2 by the in-graph memset.
__global__ void k_fc(const signed char* __restrict__ h8, const signed char* __restrict__ fc8,
                     const unsigned* __restrict__ mx_fc, float* __restrict__ out) {
    int tid = threadIdx.x;              // 128 threads = 64 b * 2 o
    int b = tid >> 1, o = tid & 1;
    const signed char* hp = h8 + b * 512;
    const char4* wp = (const char4*)(fc8 + o * 512);
    int s = 0;
    for (int i = 0; i < 64; i++) {
        u64 hv = __hip_atomic_load((const u64*)(hp + i * 8), __ATOMIC_RELAXED, __HIP_MEMORY_SCOPE_AGENT);
        char4 w0 = wp[i * 2], w1 = wp[i * 2 + 1];
        signed char hb[8];
        *(u64*)hb = hv;
        s += hb[0] * w0.x + hb[1] * w0.y + hb[2] * w0.z + hb[3] * w0.w
           + hb[4] * w1.x + hb[5] * w1.y + hb[6] * w1.z + hb[7] * w1.w;
    }
    float sc = ldexpf(1.0f, scale_exp(__uint_as_float(*mx_fc)) - 4);
    out[b * 2 + o] = (float)s * sc;     // exact: s < 2^23, pow2 scale
}

extern "C" void kernel_launch(void* const* d_in, const int* in_sizes, int n_in,
                              void* d_out, int out_size, void* d_ws, size_t ws_size,
                              hipStream_t stream) {
    (void)in_sizes; (void)n_in; (void)out_size; (void)ws_size;
    const int*   text = (const int*)d_in[0];
    const float* emb  = (const float*)d_in[2];
    const float* w_ih = (const float*)d_in[3];
    const float* w_hh = (const float*)d_in[4];
    const float* b_ih = (const float*)d_in[5];
    const float* b_hh = (const float*)d_in[6];
    const float* fc_w = (const float*)d_in[7];

    char* ws = (char*)d_ws;
    unsigned*    bar  = (unsigned*)(ws + O_BAR);
    unsigned*    mx   = (unsigned*)(ws + O_MAX);
    signed char* h8   = (signed char*)(ws + O_H8);
    signed char* fc8  = (signed char*)(ws + O_FC8);
    signed char* wih8 = (signed char*)(ws + O_WIH8);
    signed char* whh8 = (signed char*)(ws + O_WHH8);
    signed char* x8   = (signed char*)(ws + O_X8);

    // zero barrier + maxabs + h double buffer (ws re-poisoned before each call)
    hipMemsetAsync(d_ws, 0, O_H8 + 2 * BATCH * H_DIM, stream);

    k_maxabs<<<2048, 256, 0, stream>>>(emb, VOCAB * E_DIM, mx + 0);
    k_maxabs<<<256, 256, 0, stream>>>(w_ih, G4 * E_DIM, mx + 1);
    k_maxabs<<<256, 256, 0, stream>>>(w_hh, G4 * H_DIM, mx + 2);
    k_maxabs<<<1, 256, 0, stream>>>(fc_w, 2 * H_DIM, mx + 3);

    k_quantw<<<512, 256, 0, stream>>>(w_ih, G4 * E_DIM, mx + 1, wih8);
    k_quantw<<<512, 256, 0, stream>>>(w_hh, G4 * H_DIM, mx + 2, whh8);
    k_quantw<<<2, 256, 0, stream>>>(fc_w, 2 * H_DIM, mx + 3, fc8);

    k_embed<<<BATCH * S_LEN, 128, 0, stream>>>(emb, text, mx + 0, x8);

    k_lstm<<<NWG, 256, 0, stream>>>(wih8, whh8, x8, b_ih, b_hh, mx, h8, bar);

    k_fc<<<1, 128, 0, stream>>>(h8, fc8, mx + 3, (float*)d_out);
}

// Round 8
// 2908.645 us; speedup vs baseline: 1.6975x; 1.2804x over previous
//
#include <hip/hip_runtime.h>
#include <math.h>

// Problem dims
#define S_LEN  512
#define BATCH  64
#define E_DIM  512
#define H_DIM  512
#define G4     2048          // 4*H
#define VOCAB  32000
#define NWG    16            // persistent LSTM workgroups (1 per 16 CUs; trivially co-resident)

typedef int v4i __attribute__((ext_vector_type(4)));
typedef unsigned long long u64;

// Workspace layout (bytes). Total ~19.0 MiB.
// h exchange: 2 slots x 64 batches x 64 units x 16B ({8 codes, 4B tag, 4B pad})
#define O_BAR   0                         // legacy/unused (memset-covered)
#define O_MAX   256                       // 4 uints: maxabs emb, ih, hh, fc
#define O_H8    512                       // 2 * 65536 B tagged h units
#define O_FC8   131584                    // 1024 int8
#define O_WIH8  132608                    // 2048*512 int8 (1 MiB)
#define O_WHH8  (O_WIH8 + 1048576)
#define O_X8    (O_WHH8 + 1048576)        // 512*64*512 int8 (16 MiB), t-major

__device__ __forceinline__ float clampf(float x, float lo, float hi) {
    return fminf(fmaxf(x, lo), hi);
}

// k = ceil(log2(maxabs/127)) via frexp (exact, no transcendental)
__device__ __forceinline__ int scale_exp(float maxabs) {
    double t = (double)maxabs / 127.0;
    int e; double f = frexp(t, &e);
    return (f == 0.5) ? (e - 1) : e;
}

// ---- XLA-CPU / Eigen fast tanh (f32), bit-exact vs the jax-CPU golden ------
__device__ __forceinline__ float xla_tanhf(float x) {
    if (fabsf(x) < 0.0004f) return x;
    float xc = fminf(fmaxf(x, -7.90531110763549805f), 7.90531110763549805f);
    float x2 = __fmul_rn(xc, xc);
    float p = fmaf(x2, -2.76076847742355e-16f, 2.00018790482477e-13f);
    p = fmaf(x2, p, -8.60467152213735e-11f);
    p = fmaf(x2, p, 5.12229709037114e-08f);
    p = fmaf(x2, p, 1.48572235717979e-05f);
    p = fmaf(x2, p, 6.37261928875436e-04f);
    p = fmaf(x2, p, 4.89352455891786e-03f);
    p = __fmul_rn(xc, p);
    float q = fmaf(x2, 1.19825839466702e-06f, 1.18534705686654e-04f);
    q = fmaf(x2, q, 2.26843463243900e-03f);
    q = fmaf(x2, q, 4.89352518554385e-03f);
    return __fdiv_rn(p, q);
}

// ---------------- maxabs reduction ----------------
__global__ void k_maxabs(const float* __restrict__ x, int n, unsigned* __restrict__ out) {
    unsigned m = 0;
    for (int i = blockIdx.x * blockDim.x + threadIdx.x; i < n; i += gridDim.x * blockDim.x)
        m = max(m, __float_as_uint(fabsf(x[i])));
    #pragma unroll
    for (int o = 32; o > 0; o >>= 1) {
        unsigned other = (unsigned)__shfl_down((int)m, o, 64);
        m = max(m, other);
    }
    __shared__ unsigned sm[4];
    if ((threadIdx.x & 63) == 0) sm[threadIdx.x >> 6] = m;
    __syncthreads();
    if (threadIdx.x == 0) {
        unsigned r = sm[0];
        for (int w = 1; w < (int)(blockDim.x >> 6); w++) r = max(r, sm[w]);
        atomicMax(out, r);
    }
}

// ---------------- weight quantization (exact: pow2 scale) ----------------
__global__ void k_quantw(const float* __restrict__ w, int n, const unsigned* __restrict__ mx,
                         signed char* __restrict__ q) {
    float inv = ldexpf(1.0f, -scale_exp(__uint_as_float(*mx)));
    for (int i = blockIdx.x * blockDim.x + threadIdx.x; i < n; i += gridDim.x * blockDim.x) {
        float v = clampf(rintf(w[i] * inv), -128.0f, 127.0f);
        q[i] = (signed char)(int)v;
    }
}

// ---------------- embedding lookup + double quantization (exact: pow2 scales) ----
__global__ void k_embed(const float* __restrict__ emb, const int* __restrict__ text,
                        const unsigned* __restrict__ mx, signed char* __restrict__ x8) {
    int row = blockIdx.x;                       // b*S + s (text is [B,S] row-major)
    int b = row >> 9, s = row & 511;
    int tok = text[row];
    int ke = scale_exp(__uint_as_float(*mx));
    float inv = ldexpf(1.0f, -ke);
    float sc2 = ldexpf(1.0f, ke + 4);
    const float4* src = (const float4*)(emb + (size_t)tok * E_DIM);
    char4* dst = (char4*)(x8 + (size_t)(s * BATCH + b) * E_DIM);
    float4 v = src[threadIdx.x];
    char4 c;
    float q;
    q = clampf(rintf(v.x * inv), -128.f, 127.f); c.x = (signed char)(int)clampf(rintf(q * sc2), -128.f, 127.f);
    q = clampf(rintf(v.y * inv), -128.f, 127.f); c.y = (signed char)(int)clampf(rintf(q * sc2), -128.f, 127.f);
    q = clampf(rintf(v.z * inv), -128.f, 127.f); c.z = (signed char)(int)clampf(rintf(q * sc2), -128.f, 127.f);
    q = clampf(rintf(v.w * inv), -128.f, 127.f); c.w = (signed char)(int)clampf(rintf(q * sc2), -128.f, 127.f);
    dst[threadIdx.x] = c;
}

#define MKFRAG(a, b) ((v4i){(a)[0], (a)[1], (b)[0], (b)[1]})

// ---------------- persistent fused LSTM, barrier-free tagged dataflow ----------
// h units: 16B {8 codes, tag=step, pad}. Producer: one global_store_dwordx4
// sc0 sc1 per thread (write-through; tag+codes in one transaction). Consumer:
// polls its own MFMA fragments with global_load_dwordx4 sc0 sc1 until tag==t —
// the poll IS the h load. No __syncthreads in the step loop, no atomic counter,
// no fences. 2-slot buffer safety: row-partitioned reader/writer symmetry
// (a wave reaching step t+2 has observed tag t+2 on its rows from all WGs,
// whose row-owning waves therefore finished all t+1 reads). Numerics frozen.
__global__ __launch_bounds__(256, 1) void k_lstm(
    const signed char* __restrict__ wih8, const signed char* __restrict__ whh8,
    const signed char* __restrict__ x8, const float* __restrict__ b_ih,
    const float* __restrict__ b_hh, const unsigned* __restrict__ mx,
    signed char* __restrict__ h8) {
    __shared__ __attribute__((aligned(16))) signed char wih_lds[128 * 528]; // rows padded 512->528
    __shared__ __attribute__((aligned(16))) signed char hstage[BATCH * 32]; // [b][jloc] codes
    __shared__ float lut_sig[256];
    __shared__ float lut_tnh[256];

    const int g = blockIdx.x;
    const int tid = threadIdx.x;
    const int wv = tid >> 6, lane = tid & 63, l15 = lane & 15, qd4 = lane >> 4;
    const float sih = ldexpf(1.0f, scale_exp(__uint_as_float(mx[1])) - 4);
    const float shh = ldexpf(1.0f, scale_exp(__uint_as_float(mx[2])) - 4);

    // Gate LUTs via XLA formulas (bit-exact policy from R6)
    if (tid < 256) {
        float v = (float)(tid - 128) * 0.125f;
        float sg = __fadd_rn(0.5f, __fmul_rn(0.5f, xla_tanhf(__fmul_rn(0.5f, v))));
        float sc = clampf(rintf(__fmul_rn(sg, 256.0f)), 0.0f, 255.0f);
        lut_sig[tid] = sc * 0.00390625f;
        float th = xla_tanhf(v);
        float tc = clampf(rintf(__fmul_rn(th, 128.0f)), -128.0f, 127.0f);
        lut_tnh[tid] = tc * 0.0078125f;
    }

    // Stage wih slice into LDS (used only by the prefetch GEMM)
    for (int it = 0; it < 16; it++) {
        int idx = it * 256 + tid;               // 16B chunks
        int r = idx >> 5, cc = (idx & 31) * 16;
        int grow = (r >> 5) * 512 + g * 32 + (r & 31);
        *(v4i*)(wih_lds + r * 528 + cc) = *(const v4i*)(wih8 + (size_t)grow * 512 + cc);
    }

    // whh slice fragments -> registers (64 x v4i; 1 wave/SIMD by design)
    v4i whf[8][8];
    #pragma unroll
    for (int nt = 0; nt < 8; nt++) {
        int nl = nt * 16 + l15;
        size_t grow = (size_t)((nl >> 5) * 512 + g * 32 + (nl & 31)) * 512;
        #pragma unroll
        for (int k = 0; k < 8; k++)
            whf[nt][k] = *(const v4i*)(whh8 + grow + k * 64 + qd4 * 16);
    }
    __syncthreads();   // LUTs + wih_lds ready (the ONLY workgroup barrier)

    // per-lane biases for the 8 N-tiles
    float bi[8], bh[8];
    #pragma unroll
    for (int nt = 0; nt < 8; nt++) {
        int nl = nt * 16 + l15;
        int col = (nl >> 5) * 512 + g * 32 + (nl & 31);
        bi[nt] = b_ih[col];
        bh[nt] = b_hh[col];
    }

    float cst[2][4];
    #pragma unroll
    for (int jh = 0; jh < 2; jh++)
        #pragma unroll
        for (int r = 0; r < 4; r++) cst[jh][r] = 0.0f;

    // input-gate accumulators for the CURRENT step (step 0 preloop)
    v4i xacc[8];
    {
        v4i xfr[8];
        const signed char* xrow = x8 + (size_t)(wv * 16 + l15) * 512 + qd4 * 16;
        #pragma unroll
        for (int k = 0; k < 8; k++) xfr[k] = *(const v4i*)(xrow + k * 64);
        #pragma unroll
        for (int nt = 0; nt < 8; nt++) {
            v4i a = (v4i){0, 0, 0, 0};
            #pragma unroll
            for (int k = 0; k < 8; k++) {
                v4i bf = *(const v4i*)(wih_lds + (nt * 16 + l15) * 528 + k * 64 + qd4 * 16);
                a = __builtin_amdgcn_mfma_i32_16x16x64_i8(xfr[k], bf, a, 0, 0, 0);
            }
            xacc[nt] = a;
        }
    }

    const int row = wv * 16 + l15;                       // this lane's batch row
    const int pb = tid >> 2, psub = tid & 3;             // producer unit: batch, sub
    const u64 paddr_base = (u64)(h8) + (u64)(pb * 64 + g * 4 + psub) * 16;
    const u64 caddr_base = (u64)(h8) + (u64)(row * 64 + qd4 * 2) * 16;

    for (int t = 0; t < S_LEN; t++) {
        // ---- poll + load h[t] fragments (slot t&1, tag t) ----
        u64 ha = caddr_base + (u64)(t & 1) * 65536;
        int tg = t;
        v4i u0,u1,u2,u3,u4,u5,u6,u7,u8,u9,u10,u11,u12,u13,u14,u15;
        for (;;) {
            asm volatile(
                "global_load_dwordx4 %0,  %16, off sc0 sc1\n\t"
                "global_load_dwordx4 %1,  %16, off offset:16 sc0 sc1\n\t"
                "global_load_dwordx4 %2,  %16, off offset:128 sc0 sc1\n\t"
                "global_load_dwordx4 %3,  %16, off offset:144 sc0 sc1\n\t"
                "global_load_dwordx4 %4,  %16, off offset:256 sc0 sc1\n\t"
                "global_load_dwordx4 %5,  %16, off offset:272 sc0 sc1\n\t"
                "global_load_dwordx4 %6,  %16, off offset:384 sc0 sc1\n\t"
                "global_load_dwordx4 %7,  %16, off offset:400 sc0 sc1\n\t"
                "global_load_dwordx4 %8,  %16, off offset:512 sc0 sc1\n\t"
                "global_load_dwordx4 %9,  %16, off offset:528 sc0 sc1\n\t"
                "global_load_dwordx4 %10, %16, off offset:640 sc0 sc1\n\t"
                "global_load_dwordx4 %11, %16, off offset:656 sc0 sc1\n\t"
                "global_load_dwordx4 %12, %16, off offset:768 sc0 sc1\n\t"
                "global_load_dwordx4 %13, %16, off offset:784 sc0 sc1\n\t"
                "global_load_dwordx4 %14, %16, off offset:896 sc0 sc1\n\t"
                "global_load_dwordx4 %15, %16, off offset:912 sc0 sc1\n\t"
                "s_waitcnt vmcnt(0)"
                : "=&v"(u0), "=&v"(u1), "=&v"(u2), "=&v"(u3),
                  "=&v"(u4), "=&v"(u5), "=&v"(u6), "=&v"(u7),
                  "=&v"(u8), "=&v"(u9), "=&v"(u10), "=&v"(u11),
                  "=&v"(u12), "=&v"(u13), "=&v"(u14), "=&v"(u15)
                : "v"(ha)
                : "memory");
            bool ok = (u0[2] == tg) & (u1[2] == tg) & (u2[2] == tg) & (u3[2] == tg)
                    & (u4[2] == tg) & (u5[2] == tg) & (u6[2] == tg) & (u7[2] == tg)
                    & (u8[2] == tg) & (u9[2] == tg) & (u10[2] == tg) & (u11[2] == tg)
                    & (u12[2] == tg) & (u13[2] == tg) & (u14[2] == tg) & (u15[2] == tg);
            if (ok) break;
            __builtin_amdgcn_s_sleep(1);
        }
        v4i afr[8];
        afr[0] = MKFRAG(u0, u1);   afr[1] = MKFRAG(u2, u3);
        afr[2] = MKFRAG(u4, u5);   afr[3] = MKFRAG(u6, u7);
        afr[4] = MKFRAG(u8, u9);   afr[5] = MKFRAG(u10, u11);
        afr[6] = MKFRAG(u12, u13); afr[7] = MKFRAG(u14, u15);

        // ---- hh GEMM (reg-resident B) + f32 pre-activations (ref association) ----
        float pre[8][4];
        #pragma unroll
        for (int nt = 0; nt < 8; nt++) {
            v4i hacc = (v4i){0, 0, 0, 0};
            #pragma unroll
            for (int k = 0; k < 8; k++)
                hacc = __builtin_amdgcn_mfma_i32_16x16x64_i8(afr[k], whf[nt][k], hacc, 0, 0, 0);
            #pragma unroll
            for (int r = 0; r < 4; r++)
                pre[nt][r] = __fadd_rn(
                    __fadd_rn(__fadd_rn(__fmul_rn((float)xacc[nt][r], sih), bi[nt]), bh[nt]),
                    __fmul_rn((float)hacc[r], shh));
        }

        // ---- gate math (bit-exact policy); stage h codes into wave-private LDS rows ----
        #pragma unroll
        for (int jh = 0; jh < 2; jh++)
            #pragma unroll
            for (int r = 0; r < 4; r++) {
                int ii = (int)clampf(rintf(__fmul_rn(pre[0 + jh][r], 8.0f)), -128.f, 127.f) + 128;
                int fi = (int)clampf(rintf(__fmul_rn(pre[2 + jh][r], 8.0f)), -128.f, 127.f) + 128;
                int gi = (int)clampf(rintf(__fmul_rn(pre[4 + jh][r], 8.0f)), -128.f, 127.f) + 128;
                int oi = (int)clampf(rintf(__fmul_rn(pre[6 + jh][r], 8.0f)), -128.f, 127.f) + 128;
                float iq = lut_sig[ii], fq = lut_sig[fi], oq = lut_sig[oi];
                float gq = lut_tnh[gi];
                float c = __fadd_rn(__fmul_rn(fq, cst[jh][r]), __fmul_rn(iq, gq));
                cst[jh][r] = c;
                float tc32 = xla_tanhf(c);
                float tq = clampf(rintf(__fmul_rn(tc32, 128.0f)), -128.f, 127.f) * 0.0078125f;
                float hv = __fmul_rn(oq, tq);
                int hc = (int)clampf(rintf(__fmul_rn(hv, 16.0f)), -128.f, 127.f);
                int b = wv * 16 + qd4 * 4 + r;
                hstage[b * 32 + jh * 16 + l15] = (signed char)hc;
            }

        // ---- publish h[t+1]: one tagged 16B write-through store per thread ----
        // (hstage rows are wave-private: intra-wave LDS dep, no __syncthreads)
        {
            u64 codes = *(const u64*)(hstage + tid * 8);    // = hstage[pb*32 + psub*8]
            v4i sval = (v4i){(int)(codes & 0xffffffffu), (int)(codes >> 32), t + 1, 0};
            u64 pa = paddr_base + (u64)((t + 1) & 1) * 65536;
            asm volatile("global_store_dwordx4 %0, %1, off sc0 sc1"
                         :: "v"(pa), "v"(sval) : "memory");
        }

        // ---- t+1 input-gate GEMM (hides the store flight + peers' publish) ----
        if (t + 1 < S_LEN) {
            v4i xfr[8];
            const signed char* xrow = x8 + (size_t)((t + 1) * BATCH + wv * 16 + l15) * 512 + qd4 * 16;
            #pragma unroll
            for (int k = 0; k < 8; k++) xfr[k] = *(const v4i*)(xrow + k * 64);
            #pragma unroll
            for (int nt = 0; nt < 8; nt++) {
                v4i a = (v4i){0, 0, 0, 0};
                #pragma unroll
                for (int k = 0; k < 8; k++) {
                    v4i bf = *(const v4i*)(wih_lds + (nt * 16 + l15) * 528 + k * 64 + qd4 * 16);
                    a = __builtin_amdgcn_mfma_i32_16x16x64_i8(xfr[k], bf, a, 0, 0, 0);
                }
                xacc[nt] = a;
            }
        }
    }
}

// ---------------- final FC: out[1,64,2] = h_T @ fc_q^T (exact int dot) ----------
// h[512] lives in slot 0 (tagged units); read codes via relaxed agent atomics
// (bypass possibly-stale cached zero lines from the in-graph memset).
__global__ void k_fc(const signed char* __restrict__ h8, const signed char* __restrict__ fc8,
                     const unsigned* __restrict__ mx_fc, float* __restrict__ out) {
    int tid = threadIdx.x;              // 128 threads = 64 b * 2 o
    int b = tid >> 1, o = tid & 1;
    const signed char* hp = h8 + b * 1024;          // 64 units * 16B per batch row
    const char4* wp = (const char4*)(fc8 + o * 512);
    int s = 0;
    for (int i = 0; i < 64; i++) {
        u64 hv = __hip_atomic_load((const u64*)(hp + i * 16), __ATOMIC_RELAXED, __HIP_MEMORY_SCOPE_AGENT);
        char4 w0 = wp[i * 2], w1 = wp[i * 2 + 1];
        signed char hb[8];
        *(u64*)hb = hv;
        s += hb[0] * w0.x + hb[1] * w0.y + hb[2] * w0.z + hb[3] * w0.w
           + hb[4] * w1.x + hb[5] * w1.y + hb[6] * w1.z + hb[7] * w1.w;
    }
    float sc = ldexpf(1.0f, scale_exp(__uint_as_float(*mx_fc)) - 4);
    out[b * 2 + o] = (float)s * sc;     // exact: s < 2^23, pow2 scale
}

extern "C" void kernel_launch(void* const* d_in, const int* in_sizes, int n_in,
                              void* d_out, int out_size, void* d_ws, size_t ws_size,
                              hipStream_t stream) {
    (void)in_sizes; (void)n_in; (void)out_size; (void)ws_size;
    const int*   text = (const int*)d_in[0];
    const float* emb  = (const float*)d_in[2];
    const float* w_ih = (const float*)d_in[3];
    const float* w_hh = (const float*)d_in[4];
    const float* b_ih = (const float*)d_in[5];
    const float* b_hh = (const float*)d_in[6];
    const float* fc_w = (const float*)d_in[7];

    char* ws = (char*)d_ws;
    unsigned*    mx   = (unsigned*)(ws + O_MAX);
    signed char* h8   = (signed char*)(ws + O_H8);
    signed char* fc8  = (signed char*)(ws + O_FC8);
    signed char* wih8 = (signed char*)(ws + O_WIH8);
    signed char* whh8 = (signed char*)(ws + O_WHH8);
    signed char* x8   = (signed char*)(ws + O_X8);

    // zero maxabs + BOTH tagged h slots (tags=0 == step-0 sentinel; h0=0 codes)
    hipMemsetAsync(d_ws, 0, O_H8 + 2 * 65536, stream);

    k_maxabs<<<2048, 256, 0, stream>>>(emb, VOCAB * E_DIM, mx + 0);
    k_maxabs<<<256, 256, 0, stream>>>(w_ih, G4 * E_DIM, mx + 1);
    k_maxabs<<<256, 256, 0, stream>>>(w_hh, G4 * H_DIM, mx + 2);
    k_maxabs<<<1, 256, 0, stream>>>(fc_w, 2 * H_DIM, mx + 3);

    k_quantw<<<512, 256, 0, stream>>>(w_ih, G4 * E_DIM, mx + 1, wih8);
    k_quantw<<<512, 256, 0, stream>>>(w_hh, G4 * H_DIM, mx + 2, whh8);
    k_quantw<<<2, 256, 0, stream>>>(fc_w, 2 * H_DIM, mx + 3, fc8);

    k_embed<<<BATCH * S_LEN, 128, 0, stream>>>(emb, text, mx + 0, x8);

    k_lstm<<<NWG, 256, 0, stream>>>(wih8, whh8, x8, b_ih, b_hh, mx, h8);

    k_fc<<<1, 128, 0, stream>>>(h8, fc8, mx + 3, (float*)d_out);
}